// Round 2
// baseline (616.687 us; speedup 1.0000x reference)
//
#include <hip/hip_runtime.h>
#include <cstdint>
#include <cstddef>

#define B_ 4
#define S_ 2048
#define D_ 768
#define F_ 3072
#define E_ 8
#define NTOK (B_*S_)        // 8192
#define NASSIGN (NTOK*2)    // 16384 (every token has exactly 2 experts)
#define RBLK 256            // router blocks (32 tokens each)
#define FBLK 32             // fill blocks (256 tokens each)
#define MAXTILE 136         // max m-tiles: 8 XCDs x 17

typedef unsigned short u16;
typedef __attribute__((ext_vector_type(8))) __bf16 bf16x8;
typedef __attribute__((ext_vector_type(4))) float f32x4;

__device__ __forceinline__ u16 f2bf(float f) {
    unsigned int u = __builtin_bit_cast(unsigned int, f);
    u += 0x7fffu + ((u >> 16) & 1u);   // RNE
    return (u16)(u >> 16);
}

// global->LDS async copy, 16B/lane. lds base MUST be wave-uniform (m104/m108):
// HW writes lane i at lds + 16*i.
__device__ __forceinline__ void async16(const void* g, void* l) {
    __builtin_amdgcn_global_load_lds(
        (const __attribute__((address_space(1))) unsigned int*)g,
        (__attribute__((address_space(3))) unsigned int*)l, 16, 0, 0);
}

// exact-gelu x*Phi(x) via A&S 7.1.26 erf (|err|<=1.5e-7), branch-free
__device__ __forceinline__ float gelu_f(float v) {
    float z = v * 0.70710678f;
    float a = fabsf(z);
    float t = __builtin_amdgcn_rcpf(1.0f + 0.3275911f * a);
    float poly = t * (0.254829592f + t * (-0.284496736f + t * (1.421413741f +
                 t * (-1.453152027f + t * 1.061405429f))));
    float e = __expf(-z * z);
    float erf_z = copysignf(1.0f - poly * e, z);
    return 0.5f * v * (1.0f + erf_z);
}

// balanced chunked tile->XCD map (m204 bijective): XCD x owns q+(x<r) consecutive
// tiles starting at x*q+min(x,r). Fixes the xcd7 starvation of mt = xcd*17+mloc.
__device__ __forceinline__ int xcd_tile(int xcd, int mloc, int nt, int* ok) {
    int q = nt >> 3, r = nt & 7;
    int cntx = q + (xcd < r ? 1 : 0);
    *ok = (mloc < cntx);
    return xcd * q + (xcd < r ? xcd : r) + mloc;
}

// ---------------- x fp32 -> bf16 ----------------
__global__ void k_cvt_x(const float* __restrict__ x, u16* __restrict__ xb) {
    int id = blockIdx.x * 256 + threadIdx.x;     // NTOK*D_/4 threads
    float4 v = ((const float4*)x)[id];
    ushort4 o;
    o.x = f2bf(v.x); o.y = f2bf(v.y); o.z = f2bf(v.z); o.w = f2bf(v.w);
    ((ushort4*)xb)[id] = o;
}

// ------------- weight transpose+convert: in[e][R][C] f32 -> out[e][C][R] bf16 -------------
// 64x64 tile, register 4x4 transpose: 16B global loads AND 16B global stores.
__global__ __launch_bounds__(256) void k_tcvt(const float* __restrict__ in, u16* __restrict__ out, int R, int C) {
    __shared__ u16 t[64][72];   // [c][r], pitch 144B (16B-aligned rows)
    int e = blockIdx.z;
    int c0 = blockIdx.x * 64, r0 = blockIdx.y * 64;
    int tid = threadIdx.x;
    int sx = tid & 15;          // col sub-block (4 cols)
    int sy = tid >> 4;          // row sub-block (4 rows), 0..15
    const float* ip = in + (size_t)e * R * C + (size_t)(r0 + sy * 4) * C + c0 + sx * 4;
    float4 v0 = *(const float4*)(ip);
    float4 v1 = *(const float4*)(ip + C);
    float4 v2 = *(const float4*)(ip + 2 * (size_t)C);
    float4 v3 = *(const float4*)(ip + 3 * (size_t)C);
    ushort4 o;
    o.x = f2bf(v0.x); o.y = f2bf(v1.x); o.z = f2bf(v2.x); o.w = f2bf(v3.x);
    *(ushort4*)&t[sx * 4 + 0][sy * 4] = o;
    o.x = f2bf(v0.y); o.y = f2bf(v1.y); o.z = f2bf(v2.y); o.w = f2bf(v3.y);
    *(ushort4*)&t[sx * 4 + 1][sy * 4] = o;
    o.x = f2bf(v0.z); o.y = f2bf(v1.z); o.z = f2bf(v2.z); o.w = f2bf(v3.z);
    *(ushort4*)&t[sx * 4 + 2][sy * 4] = o;
    o.x = f2bf(v0.w); o.y = f2bf(v1.w); o.z = f2bf(v2.w); o.w = f2bf(v3.w);
    *(ushort4*)&t[sx * 4 + 3][sy * 4] = o;
    __syncthreads();
    // out rows (c): 64 u16 each = 8 lanes x 16B; 32 rows per pass, 2 passes
    int od = tid & 7;
    int oc = tid >> 3;
    u16* obase = out + (size_t)e * C * R;
    #pragma unroll
    for (int p = 0; p < 2; p++) {
        int c = oc + p * 32;
        *(uint4*)(obase + (size_t)(c0 + c) * R + r0 + od * 8) = *(const uint4*)&t[c][od * 8];
    }
}

// ---------------- router ----------------
__global__ __launch_bounds__(256) void k_router(
    const float* __restrict__ x, const float* __restrict__ Wr,
    float* __restrict__ usage_part, float* __restrict__ z_part,
    int* __restrict__ hist_part,
    int* __restrict__ tk_idx, float* __restrict__ tk_w)
{
    __shared__ float wrt[E_ * D_];
    __shared__ float s_usage[E_];
    __shared__ float s_z;
    __shared__ int   s_hist[E_];
    int tid = threadIdx.x;
    for (int i = tid; i < E_ * D_; i += 256) {
        int d = i >> 3, e = i & 7;
        wrt[e * D_ + d] = Wr[i];
    }
    if (tid < E_) { s_usage[tid] = 0.f; s_hist[tid] = 0; }
    if (tid == 0) s_z = 0.f;
    __syncthreads();

    int w = tid >> 6, lane = tid & 63;
    float u_acc[E_];
    #pragma unroll
    for (int e = 0; e < E_; e++) u_acc[e] = 0.f;
    float z_acc = 0.f;

    for (int it = 0; it < 8; it++) {
        int tok = blockIdx.x * 32 + it * 4 + w;
        float acc[E_];
        #pragma unroll
        for (int e = 0; e < E_; e++) acc[e] = 0.f;
        const float* xr = x + (size_t)tok * D_;
        for (int d = lane; d < D_; d += 64) {
            float xv = xr[d];
            #pragma unroll
            for (int e = 0; e < E_; e++) acc[e] += xv * wrt[e * D_ + d];
        }
        #pragma unroll
        for (int off = 32; off > 0; off >>= 1) {
            #pragma unroll
            for (int e = 0; e < E_; e++) acc[e] += __shfl_down(acc[e], off);
        }
        if (lane == 0) {
            float m = acc[0];
            #pragma unroll
            for (int e = 1; e < E_; e++) m = fmaxf(m, acc[e]);
            float p[E_], s = 0.f;
            #pragma unroll
            for (int e = 0; e < E_; e++) { p[e] = expf(acc[e] - m); s += p[e]; }
            float inv = 1.f / s;
            #pragma unroll
            for (int e = 0; e < E_; e++) { p[e] *= inv; u_acc[e] += p[e]; }
            float lse = m + logf(s);
            z_acc += lse * lse;
            int i1 = 0;
            for (int e = 1; e < E_; e++) if (p[e] > p[i1]) i1 = e;
            int i2 = -1;
            for (int e = 0; e < E_; e++) {
                if (e == i1) continue;
                if (i2 < 0 || p[e] > p[i2]) i2 = e;
            }
            float denom = p[i1] + p[i2] + 1e-8f;
            tk_idx[tok * 2 + 0] = i1; tk_idx[tok * 2 + 1] = i2;
            tk_w[tok * 2 + 0] = p[i1] / denom;
            tk_w[tok * 2 + 1] = p[i2] / denom;
            atomicAdd(&s_hist[i1], 1); atomicAdd(&s_hist[i2], 1);
        }
    }
    if (lane == 0) {
        #pragma unroll
        for (int e = 0; e < E_; e++) atomicAdd(&s_usage[e], u_acc[e]);
        atomicAdd(&s_z, z_acc);
    }
    __syncthreads();
    if (tid < E_) {
        usage_part[blockIdx.x * E_ + tid] = s_usage[tid];
        hist_part[blockIdx.x * E_ + tid]  = s_hist[tid];
    }
    if (tid == 0) z_part[blockIdx.x] = s_z;
}

// ---------------- reduce partials -> counts/offsets/tile-list + scalar losses ----------------
// also zeroes cursors (consumed later by k_fill) — k_init folded in.
__global__ __launch_bounds__(256) void k_finalize(
    const float* __restrict__ usage_part, const float* __restrict__ z_part,
    const int* __restrict__ hist_part,
    int* __restrict__ counts, int* __restrict__ offsets,
    int* __restrict__ cursors,
    int* __restrict__ tile_list,      // [0]=ntiles, [1+i]=(m0<<8)|e
    float* __restrict__ out_scalars)
{
    __shared__ float s_u[E_];
    __shared__ float s_z;
    __shared__ int   s_h[E_];
    int tid = threadIdx.x;
    if (tid < E_) { s_u[tid] = 0.f; s_h[tid] = 0; cursors[tid] = 0; }
    if (tid == 0) s_z = 0.f;
    __syncthreads();

    float u[E_]; int h[E_];
    #pragma unroll
    for (int e = 0; e < E_; e++) { u[e] = usage_part[tid * E_ + e]; h[e] = hist_part[tid * E_ + e]; }
    float z = z_part[tid];
    #pragma unroll
    for (int off = 32; off > 0; off >>= 1) {
        #pragma unroll
        for (int e = 0; e < E_; e++) {
            u[e] += __shfl_down(u[e], off);
            h[e] += __shfl_down(h[e], off);
        }
        z += __shfl_down(z, off);
    }
    if ((tid & 63) == 0) {
        #pragma unroll
        for (int e = 0; e < E_; e++) { atomicAdd(&s_u[e], u[e]); atomicAdd(&s_h[e], h[e]); }
        atomicAdd(&s_z, z);
    }
    __syncthreads();
    if (tid == 0) {
        int o = 0, nt = 0;
        for (int e = 0; e < E_; e++) {
            int c = s_h[e];
            counts[e] = c; offsets[e] = o; o += c;
            for (int m0 = 0; m0 < c; m0 += 128) tile_list[1 + nt++] = (m0 << 8) | e;
        }
        tile_list[0] = nt;
        float uu[E_], mean = 0.f;
        for (int e = 0; e < E_; e++) { uu[e] = s_u[e] / (float)NTOK; mean += uu[e]; }
        mean /= (float)E_;
        float var = 0.f;
        for (int e = 0; e < E_; e++) { float d = uu[e] - mean; var += d * d; }
        var /= (float)E_;
        out_scalars[0] = var / (mean * mean + 1e-8f) * (float)E_ * 0.01f;  // lb_loss
        out_scalars[1] = (s_z / (float)NTOK) * 0.001f;                      // z_loss
    }
}

// ---------------- build compact per-expert assignment lists ----------------
__global__ __launch_bounds__(256) void k_fill(
    const int* __restrict__ tk_idx, const float* __restrict__ tk_w,
    const int* __restrict__ offsets, int* __restrict__ cursors,
    int* __restrict__ assign_token, float* __restrict__ assign_weight)
{
    __shared__ int l_cnt[E_];
    __shared__ int l_base[E_];
    int tid = threadIdx.x;
    if (tid < E_) l_cnt[tid] = 0;
    __syncthreads();
    int t = blockIdx.x * 256 + tid;
    int e0 = tk_idx[t * 2 + 0], e1 = tk_idx[t * 2 + 1];
    int r0 = atomicAdd(&l_cnt[e0], 1);
    int r1 = atomicAdd(&l_cnt[e1], 1);
    __syncthreads();
    if (tid < E_) l_base[tid] = atomicAdd(&cursors[tid], l_cnt[tid]);
    __syncthreads();
    int row0 = offsets[e0] + l_base[e0] + r0;
    int row1 = offsets[e1] + l_base[e1] + r1;
    assign_token[row0] = t; assign_weight[row0] = tk_w[t * 2 + 0];
    assign_token[row1] = t; assign_weight[row1] = tk_w[t * 2 + 1];
}

// ---------------- GEMM1: h = gelu(gather(x) @ W1[e] + b1[e]) ----------------
// 1D grid, XCD-swizzled: xcd=bid&7, j=bid>>3, nx=j/17, mloc=j%17, balanced chunk map.
// m-siblings sharing the w1t slice (e,n0) run adjacently on ONE XCD -> L2 reuse.
__global__ __launch_bounds__(256) void k_gemm1(
    const u16* __restrict__ xb, const u16* __restrict__ w1t,
    const float* __restrict__ b1,
    const int* __restrict__ counts, const int* __restrict__ offsets,
    const int* __restrict__ tile_list,
    const int* __restrict__ assign_token, u16* __restrict__ h)
{
    int bid = blockIdx.x;
    int xcd = bid & 7;
    int j = bid >> 3;
    int nx = j / 17;
    int mloc = j % 17;
    int nt = tile_list[0];
    int ok;
    int mt = xcd_tile(xcd, mloc, nt, &ok);
    if (!ok) return;
    int packed = tile_list[1 + mt];
    int e = packed & 0xff;
    int m0 = packed >> 8;
    int cnt = counts[e];
    int off = offsets[e];
    int n0 = nx * 128;

    __shared__ __align__(16) u16 SM[16384];   // As dbuf @0, Bs dbuf @8192 (u16 idx)
    char* smb = (char*)SM;

    int tid = threadIdx.x;
    int w = tid >> 6, lane = tid & 63;
    int rA = lane >> 2;
    // XOR-swizzled k-chunk for staging: lane (rA,c) loads global chunk c^(rA&3)
    int colk = ((lane & 3) ^ (rA & 3)) * 8;
    int r0 = (w * 2 + 0) * 16 + rA;
    int r1 = (w * 2 + 1) * 16 + rA;

    int c0b = __builtin_amdgcn_readfirstlane((w * 2 + 0) * 1024);
    int c1b = __builtin_amdgcn_readfirstlane((w * 2 + 1) * 1024);

    int g0 = m0 + r0; if (g0 > cnt - 1) g0 = cnt - 1;
    int g1 = m0 + r1; if (g1 > cnt - 1) g1 = cnt - 1;
    const u16* agp0 = xb + (size_t)assign_token[off + g0] * D_ + colk;
    const u16* agp1 = xb + (size_t)assign_token[off + g1] * D_ + colk;
    const u16* bgp0 = w1t + ((size_t)e * F_ + n0 + r0) * D_ + colk;
    const u16* bgp1 = w1t + ((size_t)e * F_ + n0 + r1) * D_ + colk;

    f32x4 acc[4][4];
    #pragma unroll
    for (int i = 0; i < 4; i++)
        #pragma unroll
        for (int j2 = 0; j2 < 4; j2++) acc[i][j2] = (f32x4){0.f, 0.f, 0.f, 0.f};

    int wm = (w >> 1) * 64, wn = (w & 1) * 64;
    int fm = lane & 15;
    int slot = ((lane >> 4) ^ (fm & 3)) * 8;   // swizzled fragment slot

    #define STAGE1(buf, kk) do { \
        async16(agp0 + (kk), smb + (buf) * 8192 + c0b); \
        async16(agp1 + (kk), smb + (buf) * 8192 + c1b); \
        async16(bgp0 + (kk), smb + 16384 + (buf) * 8192 + c0b); \
        async16(bgp1 + (kk), smb + 16384 + (buf) * 8192 + c1b); \
    } while (0)
    #define COMPUTE1(buf) do { \
        const u16* Ab = SM + (buf) * 4096; \
        const u16* Bb = SM + 8192 + (buf) * 4096; \
        bf16x8 af[4], bfr[4]; \
        _Pragma("unroll") \
        for (int i = 0; i < 4; i++) af[i] = *(const bf16x8*)&Ab[(wm + i * 16 + fm) * 32 + slot]; \
        _Pragma("unroll") \
        for (int j2 = 0; j2 < 4; j2++) bfr[j2] = *(const bf16x8*)&Bb[(wn + j2 * 16 + fm) * 32 + slot]; \
        _Pragma("unroll") \
        for (int i = 0; i < 4; i++) \
            _Pragma("unroll") \
            for (int j2 = 0; j2 < 4; j2++) \
                acc[i][j2] = __builtin_amdgcn_mfma_f32_16x16x32_bf16(af[i], bfr[j2], acc[i][j2], 0, 0, 0); \
    } while (0)

    STAGE1(0, 0);
    __syncthreads();
    for (int kk = 0; kk < D_; kk += 64) {
        STAGE1(1, kk + 32);
        COMPUTE1(0);
        __syncthreads();
        if (kk + 64 < D_) STAGE1(0, kk + 64);
        COMPUTE1(1);
        __syncthreads();
    }
    #undef STAGE1
    #undef COMPUTE1

    // ---- epilogue: gelu+cvt -> per-wave swizzled LDS tile -> coalesced uint4 stores ----
    int rbase = (lane >> 4) * 4;
    u16* tb = SM + w * 4096;          // 64x64 u16 (8 KB), XOR-swizzled by (m&7)
    float biasv[4];
    #pragma unroll
    for (int j2 = 0; j2 < 4; j2++) biasv[j2] = b1[e * F_ + n0 + wn + j2 * 16 + fm];
    #pragma unroll
    for (int i = 0; i < 4; i++)
        #pragma unroll
        for (int j2 = 0; j2 < 4; j2++)
            #pragma unroll
            for (int r = 0; r < 4; r++) {
                int m_l = i * 16 + rbase + r;
                int f_l = j2 * 16 + fm;
                u16 q = f2bf(gelu_f(acc[i][j2][r] + biasv[j2]));
                tb[m_l * 64 + ((((f_l >> 3) ^ (m_l & 7)) << 3) | (f_l & 7))] = q;
            }
    __syncthreads();
    #pragma unroll
    for (int s = 0; s < 8; s++) {
        int m_l = s * 8 + (lane >> 3);
        int c = lane & 7;
        uint4 vv = *(const uint4*)&tb[m_l * 64 + ((c ^ (m_l & 7)) << 3)];
        int m = m0 + wm + m_l;
        if (m < cnt)
            *(uint4*)&h[(size_t)(off + m) * F_ + n0 + wn + c * 8] = vv;
    }
}

// ---------------- GEMM2: out[token] += (h @ W2[e] + b2[e]) * weight (atomic combine) ----------------
// 1D grid, XCD-swizzled + K-split x2 for occupancy (was 3 blocks/CU, LDS cap is 5):
// xcd=bid&7, j=bid>>3, mloc=j/12, rem=j%12, nx=rem%6, kh=rem/6.
// The 12 (nx,kh)-siblings of each m-tile run adjacently on ONE XCD -> h slice L2-resident.
// Atomic combine makes K-split free; bias added only by kh==0.
__global__ __launch_bounds__(256) void k_gemm2(
    const u16* __restrict__ h, const u16* __restrict__ w2t,
    const float* __restrict__ b2,
    const int* __restrict__ counts, const int* __restrict__ offsets,
    const int* __restrict__ tile_list,
    const int* __restrict__ assign_token, const float* __restrict__ assign_weight,
    float* __restrict__ out)
{
    int bid = blockIdx.x;
    int xcd = bid & 7;
    int j = bid >> 3;
    int mloc = j / 12;
    int rem = j % 12;
    int nx = rem % 6;
    int kh = rem / 6;
    int nt = tile_list[0];
    int ok;
    int mt = xcd_tile(xcd, mloc, nt, &ok);
    if (!ok) return;
    int packed = tile_list[1 + mt];
    int e = packed & 0xff;
    int m0 = packed >> 8;
    int cnt = counts[e];
    int off = offsets[e];
    int n0 = nx * 128;
    int kbase = kh * (F_ / 2);
    int kend = kbase + F_ / 2;

    __shared__ __align__(16) u16 SM[16384];
    char* smb = (char*)SM;

    int tid = threadIdx.x;
    int w = tid >> 6, lane = tid & 63;
    int rA = lane >> 2;
    int colk = ((lane & 3) ^ (rA & 3)) * 8;
    int r0 = (w * 2 + 0) * 16 + rA;
    int r1 = (w * 2 + 1) * 16 + rA;

    int c0b = __builtin_amdgcn_readfirstlane((w * 2 + 0) * 1024);
    int c1b = __builtin_amdgcn_readfirstlane((w * 2 + 1) * 1024);

    // rows beyond cnt over-read hbuf slack rows (allocated), masked at store
    const u16* agp0 = h + (size_t)(off + m0 + r0) * F_ + colk;
    const u16* agp1 = h + (size_t)(off + m0 + r1) * F_ + colk;
    const u16* bgp0 = w2t + ((size_t)e * D_ + n0 + r0) * F_ + colk;
    const u16* bgp1 = w2t + ((size_t)e * D_ + n0 + r1) * F_ + colk;

    f32x4 acc[4][4];
    #pragma unroll
    for (int i = 0; i < 4; i++)
        #pragma unroll
        for (int j2 = 0; j2 < 4; j2++) acc[i][j2] = (f32x4){0.f, 0.f, 0.f, 0.f};

    int wm = (w >> 1) * 64, wn = (w & 1) * 64;
    int fm = lane & 15;
    int slot = ((lane >> 4) ^ (fm & 3)) * 8;

    #define STAGE2(buf, kk) do { \
        async16(agp0 + (kk), smb + (buf) * 8192 + c0b); \
        async16(agp1 + (kk), smb + (buf) * 8192 + c1b); \
        async16(bgp0 + (kk), smb + 16384 + (buf) * 8192 + c0b); \
        async16(bgp1 + (kk), smb + 16384 + (buf) * 8192 + c1b); \
    } while (0)
    #define COMPUTE2(buf) do { \
        const u16* Ab = SM + (buf) * 4096; \
        const u16* Bb = SM + 8192 + (buf) * 4096; \
        bf16x8 af[4], bfr[4]; \
        _Pragma("unroll") \
        for (int i = 0; i < 4; i++) af[i] = *(const bf16x8*)&Ab[(wm + i * 16 + fm) * 32 + slot]; \
        _Pragma("unroll") \
        for (int j2 = 0; j2 < 4; j2++) bfr[j2] = *(const bf16x8*)&Bb[(wn + j2 * 16 + fm) * 32 + slot]; \
        _Pragma("unroll") \
        for (int i = 0; i < 4; i++) \
            _Pragma("unroll") \
            for (int j2 = 0; j2 < 4; j2++) \
                acc[i][j2] = __builtin_amdgcn_mfma_f32_16x16x32_bf16(af[i], bfr[j2], acc[i][j2], 0, 0, 0); \
    } while (0)

    STAGE2(0, kbase);
    __syncthreads();
    for (int kk = kbase; kk < kend; kk += 64) {
        STAGE2(1, kk + 32);
        COMPUTE2(0);
        __syncthreads();
        if (kk + 64 < kend) STAGE2(0, kk + 64);
        COMPUTE2(1);
        __syncthreads();
    }
    #undef STAGE2
    #undef COMPUTE2

    int rbase = (lane >> 4) * 4;
    float biasv[4];
    #pragma unroll
    for (int j2 = 0; j2 < 4; j2++)
        biasv[j2] = (kh == 0) ? b2[e * D_ + n0 + wn + j2 * 16 + fm] : 0.f;
    #pragma unroll
    for (int i = 0; i < 4; i++)
        #pragma unroll
        for (int r = 0; r < 4; r++) {
            int m = m0 + wm + i * 16 + rbase + r;
            if (m < cnt) {
                int t = assign_token[off + m];
                float wg = assign_weight[off + m];
                float* orow = out + (size_t)t * D_ + n0 + wn + fm;
                #pragma unroll
                for (int j2 = 0; j2 < 4; j2++)
                    unsafeAtomicAdd(orow + j2 * 16, (acc[i][j2][r] + biasv[j2]) * wg);
            }
        }
}

extern "C" void kernel_launch(void* const* d_in, const int* in_sizes, int n_in,
                              void* d_out, int out_size, void* d_ws, size_t ws_size,
                              hipStream_t stream)
{
    const float* x  = (const float*)d_in[0];
    const float* Wr = (const float*)d_in[1];
    const float* W1 = (const float*)d_in[2];
    const float* b1 = (const float*)d_in[3];
    const float* W2 = (const float*)d_in[4];
    const float* b2 = (const float*)d_in[5];
    float* out = (float*)d_out;

    char* base = (char*)d_ws;
    size_t o = 0;
    auto alloc = [&](size_t bytes) {
        char* r = base + o;
        o += (bytes + 255) & ~(size_t)255;
        return r;
    };
    int*   counts        = (int*)  alloc(E_ * 4);
    int*   cursors       = (int*)  alloc(E_ * 4);
    int*   offsets       = (int*)  alloc(E_ * 4);
    int*   tile_list     = (int*)  alloc(256 * 4);
    float* usage_part    = (float*)alloc((size_t)RBLK * E_ * 4);
    float* z_part        = (float*)alloc((size_t)RBLK * 4);
    int*   hist_part     = (int*)  alloc((size_t)RBLK * E_ * 4);
    int*   tk_idx        = (int*)  alloc((size_t)NTOK * 2 * 4);
    float* tk_w          = (float*)alloc((size_t)NTOK * 2 * 4);
    int*   assign_token  = (int*)  alloc((size_t)NASSIGN * 4);
    float* assign_weight = (float*)alloc((size_t)NASSIGN * 4);
    u16*   xb            = (u16*)  alloc((size_t)NTOK * D_ * 2);
    u16*   w1t           = (u16*)  alloc((size_t)E_ * F_ * D_ * 2);
    u16*   w2t           = (u16*)  alloc((size_t)E_ * D_ * F_ * 2);
    u16*   hbuf          = (u16*)  alloc((size_t)(NASSIGN + 128) * F_ * 2);  // +128 over-read slack

    hipMemsetAsync(d_out, 0, (size_t)out_size * 4, stream);
    k_cvt_x<<<dim3(NTOK * D_ / 1024), dim3(256), 0, stream>>>(x, xb);
    k_tcvt<<<dim3(F_ / 64, D_ / 64, E_), dim3(256), 0, stream>>>(W1, w1t, D_, F_);
    k_tcvt<<<dim3(D_ / 64, F_ / 64, E_), dim3(256), 0, stream>>>(W2, w2t, F_, D_);
    k_router<<<dim3(RBLK), dim3(256), 0, stream>>>(x, Wr, usage_part, z_part, hist_part, tk_idx, tk_w);
    k_finalize<<<dim3(1), dim3(256), 0, stream>>>(usage_part, z_part, hist_part, counts, offsets,
                                                  cursors, tile_list, out + (size_t)NTOK * D_);
    k_fill<<<dim3(FBLK), dim3(256), 0, stream>>>(tk_idx, tk_w, offsets, cursors, assign_token, assign_weight);
    k_gemm1<<<dim3(8 * 17 * (F_ / 128)), dim3(256), 0, stream>>>(xb, w1t, b1, counts, offsets, tile_list,
                                                                 assign_token, hbuf);
    k_gemm2<<<dim3(8 * 17 * (D_ / 128) * 2), dim3(256), 0, stream>>>(hbuf, w2t, b2, counts, offsets, tile_list,
                                                                     assign_token, assign_weight, out);
}

// Round 4
// 529.747 us; speedup vs baseline: 1.1641x; 1.1641x over previous
//
#include <hip/hip_runtime.h>
#include <cstdint>
#include <cstddef>

#define B_ 4
#define S_ 2048
#define D_ 768
#define F_ 3072
#define E_ 8
#define NTOK (B_*S_)        // 8192
#define NASSIGN (NTOK*2)    // 16384 (every token has exactly 2 experts)
#define RBLK 256            // router blocks (32 tokens each)
#define FBLK 32             // fill blocks (256 tokens each)

typedef unsigned short u16;
typedef __attribute__((ext_vector_type(8))) __bf16 bf16x8;
typedef __attribute__((ext_vector_type(4))) float f32x4;

__device__ __forceinline__ u16 f2bf(float f) {
    unsigned int u = __builtin_bit_cast(unsigned int, f);
    u += 0x7fffu + ((u >> 16) & 1u);   // RNE
    return (u16)(u >> 16);
}

// global->LDS async copy, 16B/lane. lds base MUST be wave-uniform (m104/m108):
// HW writes lane i at lds + 16*i.
__device__ __forceinline__ void async16(const void* g, void* l) {
    __builtin_amdgcn_global_load_lds(
        (const __attribute__((address_space(1))) unsigned int*)g,
        (__attribute__((address_space(3))) unsigned int*)l, 16, 0, 0);
}

// Counted-vmcnt pipeline waits (T3/T4): keep the NEXT tile's 4 global_load_lds
// in flight across the barrier; only the oldest 4 (current tile) must have
// landed. CRITICAL (R3 post-mortem): raw s_barrier does NOT drain lgkmcnt —
// without lgkmcnt(0) a wave can signal the barrier with ds_reads of the
// about-to-be-restaged buffer still in flight, racing another wave's
// global_load_lds overwrite. lgkmcnt(0) is near-free (ds_reads were already
// consumed by MFMAs); vmcnt stays counted so prefetch overlaps the barrier.
#define PWAIT4 do { \
    asm volatile("s_waitcnt vmcnt(4) lgkmcnt(0)" ::: "memory"); \
    __builtin_amdgcn_s_barrier(); \
    asm volatile("" ::: "memory"); \
} while (0)
#define PWAIT0 do { \
    asm volatile("s_waitcnt vmcnt(0) lgkmcnt(0)" ::: "memory"); \
    __builtin_amdgcn_s_barrier(); \
    asm volatile("" ::: "memory"); \
} while (0)

// exact-gelu x*Phi(x) via A&S 7.1.26 erf (|err|<=1.5e-7), branch-free
__device__ __forceinline__ float gelu_f(float v) {
    float z = v * 0.70710678f;
    float a = fabsf(z);
    float t = __builtin_amdgcn_rcpf(1.0f + 0.3275911f * a);
    float poly = t * (0.254829592f + t * (-0.284496736f + t * (1.421413741f +
                 t * (-1.453152027f + t * 1.061405429f))));
    float e = __expf(-z * z);
    float erf_z = copysignf(1.0f - poly * e, z);
    return 0.5f * v * (1.0f + erf_z);
}

// balanced chunked tile->XCD map (m204 bijective): XCD x owns q+(x<r) consecutive
// tiles starting at x*q+min(x,r).
__device__ __forceinline__ int xcd_tile(int xcd, int mloc, int nt, int* ok) {
    int q = nt >> 3, r = nt & 7;
    int cntx = q + (xcd < r ? 1 : 0);
    *ok = (mloc < cntx);
    return xcd * q + (xcd < r ? xcd : r) + mloc;
}

// ---------------- x fp32 -> bf16 ----------------
__global__ void k_cvt_x(const float* __restrict__ x, u16* __restrict__ xb) {
    int id = blockIdx.x * 256 + threadIdx.x;     // NTOK*D_/4 threads
    float4 v = ((const float4*)x)[id];
    ushort4 o;
    o.x = f2bf(v.x); o.y = f2bf(v.y); o.z = f2bf(v.z); o.w = f2bf(v.w);
    ((ushort4*)xb)[id] = o;
}

// ------------- weight transpose+convert: in[e][R][C] f32 -> out[e][C][R] bf16 -------------
// 64x64 tile, register 4x4 transpose: 16B global loads AND 16B global stores.
__global__ __launch_bounds__(256) void k_tcvt(const float* __restrict__ in, u16* __restrict__ out, int R, int C) {
    __shared__ u16 t[64][72];   // [c][r], pitch 144B (16B-aligned rows)
    int e = blockIdx.z;
    int c0 = blockIdx.x * 64, r0 = blockIdx.y * 64;
    int tid = threadIdx.x;
    int sx = tid & 15;          // col sub-block (4 cols)
    int sy = tid >> 4;          // row sub-block (4 rows), 0..15
    const float* ip = in + (size_t)e * R * C + (size_t)(r0 + sy * 4) * C + c0 + sx * 4;
    float4 v0 = *(const float4*)(ip);
    float4 v1 = *(const float4*)(ip + C);
    float4 v2 = *(const float4*)(ip + 2 * (size_t)C);
    float4 v3 = *(const float4*)(ip + 3 * (size_t)C);
    ushort4 o;
    o.x = f2bf(v0.x); o.y = f2bf(v1.x); o.z = f2bf(v2.x); o.w = f2bf(v3.x);
    *(ushort4*)&t[sx * 4 + 0][sy * 4] = o;
    o.x = f2bf(v0.y); o.y = f2bf(v1.y); o.z = f2bf(v2.y); o.w = f2bf(v3.y);
    *(ushort4*)&t[sx * 4 + 1][sy * 4] = o;
    o.x = f2bf(v0.z); o.y = f2bf(v1.z); o.z = f2bf(v2.z); o.w = f2bf(v3.z);
    *(ushort4*)&t[sx * 4 + 2][sy * 4] = o;
    o.x = f2bf(v0.w); o.y = f2bf(v1.w); o.z = f2bf(v2.w); o.w = f2bf(v3.w);
    *(ushort4*)&t[sx * 4 + 3][sy * 4] = o;
    __syncthreads();
    // out rows (c): 64 u16 each = 8 lanes x 16B; 32 rows per pass, 2 passes
    int od = tid & 7;
    int oc = tid >> 3;
    u16* obase = out + (size_t)e * C * R;
    #pragma unroll
    for (int p = 0; p < 2; p++) {
        int c = oc + p * 32;
        *(uint4*)(obase + (size_t)(c0 + c) * R + r0 + od * 8) = *(const uint4*)&t[c][od * 8];
    }
}

// ---------------- router ----------------
__global__ __launch_bounds__(256) void k_router(
    const float* __restrict__ x, const float* __restrict__ Wr,
    float* __restrict__ usage_part, float* __restrict__ z_part,
    int* __restrict__ hist_part,
    int* __restrict__ tk_idx, float* __restrict__ tk_w)
{
    __shared__ float wrt[E_ * D_];
    __shared__ float s_usage[E_];
    __shared__ float s_z;
    __shared__ int   s_hist[E_];
    int tid = threadIdx.x;
    for (int i = tid; i < E_ * D_; i += 256) {
        int d = i >> 3, e = i & 7;
        wrt[e * D_ + d] = Wr[i];
    }
    if (tid < E_) { s_usage[tid] = 0.f; s_hist[tid] = 0; }
    if (tid == 0) s_z = 0.f;
    __syncthreads();

    int w = tid >> 6, lane = tid & 63;
    float u_acc[E_];
    #pragma unroll
    for (int e = 0; e < E_; e++) u_acc[e] = 0.f;
    float z_acc = 0.f;

    for (int it = 0; it < 8; it++) {
        int tok = blockIdx.x * 32 + it * 4 + w;
        float acc[E_];
        #pragma unroll
        for (int e = 0; e < E_; e++) acc[e] = 0.f;
        const float* xr = x + (size_t)tok * D_;
        for (int d = lane; d < D_; d += 64) {
            float xv = xr[d];
            #pragma unroll
            for (int e = 0; e < E_; e++) acc[e] += xv * wrt[e * D_ + d];
        }
        #pragma unroll
        for (int off = 32; off > 0; off >>= 1) {
            #pragma unroll
            for (int e = 0; e < E_; e++) acc[e] += __shfl_down(acc[e], off);
        }
        if (lane == 0) {
            float m = acc[0];
            #pragma unroll
            for (int e = 1; e < E_; e++) m = fmaxf(m, acc[e]);
            float p[E_], s = 0.f;
            #pragma unroll
            for (int e = 0; e < E_; e++) { p[e] = expf(acc[e] - m); s += p[e]; }
            float inv = 1.f / s;
            #pragma unroll
            for (int e = 0; e < E_; e++) { p[e] *= inv; u_acc[e] += p[e]; }
            float lse = m + logf(s);
            z_acc += lse * lse;
            int i1 = 0;
            for (int e = 1; e < E_; e++) if (p[e] > p[i1]) i1 = e;
            int i2 = -1;
            for (int e = 0; e < E_; e++) {
                if (e == i1) continue;
                if (i2 < 0 || p[e] > p[i2]) i2 = e;
            }
            float denom = p[i1] + p[i2] + 1e-8f;
            tk_idx[tok * 2 + 0] = i1; tk_idx[tok * 2 + 1] = i2;
            tk_w[tok * 2 + 0] = p[i1] / denom;
            tk_w[tok * 2 + 1] = p[i2] / denom;
            atomicAdd(&s_hist[i1], 1); atomicAdd(&s_hist[i2], 1);
        }
    }
    if (lane == 0) {
        #pragma unroll
        for (int e = 0; e < E_; e++) atomicAdd(&s_usage[e], u_acc[e]);
        atomicAdd(&s_z, z_acc);
    }
    __syncthreads();
    if (tid < E_) {
        usage_part[blockIdx.x * E_ + tid] = s_usage[tid];
        hist_part[blockIdx.x * E_ + tid]  = s_hist[tid];
    }
    if (tid == 0) z_part[blockIdx.x] = s_z;
}

// ---------------- reduce partials -> counts/offsets/tile-list + scalar losses ----------------
// also zeroes cursors (consumed later by k_fill) — k_init folded in.
__global__ __launch_bounds__(256) void k_finalize(
    const float* __restrict__ usage_part, const float* __restrict__ z_part,
    const int* __restrict__ hist_part,
    int* __restrict__ counts, int* __restrict__ offsets,
    int* __restrict__ cursors,
    int* __restrict__ tile_list,      // [0]=ntiles, [1+i]=(m0<<8)|e
    float* __restrict__ out_scalars)
{
    __shared__ float s_u[E_];
    __shared__ float s_z;
    __shared__ int   s_h[E_];
    int tid = threadIdx.x;
    if (tid < E_) { s_u[tid] = 0.f; s_h[tid] = 0; cursors[tid] = 0; }
    if (tid == 0) s_z = 0.f;
    __syncthreads();

    float u[E_]; int h[E_];
    #pragma unroll
    for (int e = 0; e < E_; e++) { u[e] = usage_part[tid * E_ + e]; h[e] = hist_part[tid * E_ + e]; }
    float z = z_part[tid];
    #pragma unroll
    for (int off = 32; off > 0; off >>= 1) {
        #pragma unroll
        for (int e = 0; e < E_; e++) {
            u[e] += __shfl_down(u[e], off);
            h[e] += __shfl_down(h[e], off);
        }
        z += __shfl_down(z, off);
    }
    if ((tid & 63) == 0) {
        #pragma unroll
        for (int e = 0; e < E_; e++) { atomicAdd(&s_u[e], u[e]); atomicAdd(&s_h[e], h[e]); }
        atomicAdd(&s_z, z);
    }
    __syncthreads();
    if (tid == 0) {
        int o = 0, nt = 0;
        for (int e = 0; e < E_; e++) {
            int c = s_h[e];
            counts[e] = c; offsets[e] = o; o += c;
            for (int m0 = 0; m0 < c; m0 += 128) tile_list[1 + nt++] = (m0 << 8) | e;
        }
        tile_list[0] = nt;
        float uu[E_], mean = 0.f;
        for (int e = 0; e < E_; e++) { uu[e] = s_u[e] / (float)NTOK; mean += uu[e]; }
        mean /= (float)E_;
        float var = 0.f;
        for (int e = 0; e < E_; e++) { float d = uu[e] - mean; var += d * d; }
        var /= (float)E_;
        out_scalars[0] = var / (mean * mean + 1e-8f) * (float)E_ * 0.01f;  // lb_loss
        out_scalars[1] = (s_z / (float)NTOK) * 0.001f;                      // z_loss
    }
}

// ---------------- build compact per-expert assignment lists ----------------
__global__ __launch_bounds__(256) void k_fill(
    const int* __restrict__ tk_idx, const float* __restrict__ tk_w,
    const int* __restrict__ offsets, int* __restrict__ cursors,
    int* __restrict__ assign_token, float* __restrict__ assign_weight)
{
    __shared__ int l_cnt[E_];
    __shared__ int l_base[E_];
    int tid = threadIdx.x;
    if (tid < E_) l_cnt[tid] = 0;
    __syncthreads();
    int t = blockIdx.x * 256 + tid;
    int e0 = tk_idx[t * 2 + 0], e1 = tk_idx[t * 2 + 1];
    int r0 = atomicAdd(&l_cnt[e0], 1);
    int r1 = atomicAdd(&l_cnt[e1], 1);
    __syncthreads();
    if (tid < E_) l_base[tid] = atomicAdd(&cursors[tid], l_cnt[tid]);
    __syncthreads();
    int row0 = offsets[e0] + l_base[e0] + r0;
    int row1 = offsets[e1] + l_base[e1] + r1;
    assign_token[row0] = t; assign_weight[row0] = tk_w[t * 2 + 0];
    assign_token[row1] = t; assign_weight[row1] = tk_w[t * 2 + 1];
}

// ---------------- GEMM1: h = gelu(gather(x) @ W1[e] + b1[e]) ----------------
// 3-buffer LDS rotation + counted vmcnt(4)+lgkmcnt(0): next tile's loads stay
// in flight across the barrier (T3/T4) — HBM/L2 latency hides under MFMA.
__global__ __launch_bounds__(256) void k_gemm1(
    const u16* __restrict__ xb, const u16* __restrict__ w1t,
    const float* __restrict__ b1,
    const int* __restrict__ counts, const int* __restrict__ offsets,
    const int* __restrict__ tile_list,
    const int* __restrict__ assign_token, u16* __restrict__ h)
{
    int bid = blockIdx.x;
    int xcd = bid & 7;
    int j = bid >> 3;
    int nx = j / 17;
    int mloc = j % 17;
    int nt = tile_list[0];
    int ok;
    int mt = xcd_tile(xcd, mloc, nt, &ok);
    if (!ok) return;
    int packed = tile_list[1 + mt];
    int e = packed & 0xff;
    int m0 = packed >> 8;
    int cnt = counts[e];
    int off = offsets[e];
    int n0 = nx * 128;

    // 3-way rotation: A bufs @ bytes 0/8K/16K, B bufs @ bytes 24K/32K/40K (48 KB)
    __shared__ __align__(16) u16 SM[24576];
    char* smb = (char*)SM;

    int tid = threadIdx.x;
    int w = tid >> 6, lane = tid & 63;
    int rA = lane >> 2;
    // XOR-swizzled k-chunk for staging: lane (rA,c) loads global chunk c^(rA&3)
    int colk = ((lane & 3) ^ (rA & 3)) * 8;
    int r0 = (w * 2 + 0) * 16 + rA;
    int r1 = (w * 2 + 1) * 16 + rA;

    int c0b = __builtin_amdgcn_readfirstlane((w * 2 + 0) * 1024);
    int c1b = __builtin_amdgcn_readfirstlane((w * 2 + 1) * 1024);

    int g0 = m0 + r0; if (g0 > cnt - 1) g0 = cnt - 1;
    int g1 = m0 + r1; if (g1 > cnt - 1) g1 = cnt - 1;
    const u16* agp0 = xb + (size_t)assign_token[off + g0] * D_ + colk;
    const u16* agp1 = xb + (size_t)assign_token[off + g1] * D_ + colk;
    const u16* bgp0 = w1t + ((size_t)e * F_ + n0 + r0) * D_ + colk;
    const u16* bgp1 = w1t + ((size_t)e * F_ + n0 + r1) * D_ + colk;

    f32x4 acc[4][4];
    #pragma unroll
    for (int i = 0; i < 4; i++)
        #pragma unroll
        for (int j2 = 0; j2 < 4; j2++) acc[i][j2] = (f32x4){0.f, 0.f, 0.f, 0.f};

    int wm = (w >> 1) * 64, wn = (w & 1) * 64;
    int fm = lane & 15;
    int slot = ((lane >> 4) ^ (fm & 3)) * 8;   // swizzled fragment slot

    // Prefetch epilogue VMEM (bias) BEFORE any STAGE and pin it retired, so no
    // stray VMEM op perturbs the loop's vmcnt bookkeeping.
    float biasv[4];
    #pragma unroll
    for (int j2 = 0; j2 < 4; j2++) {
        biasv[j2] = b1[e * F_ + n0 + wn + j2 * 16 + fm];
        asm volatile("" : "+v"(biasv[j2]));
    }

    #define STAGE1(p, kk) do { \
        char* Ad = smb + (p) * 8192; \
        char* Bd = smb + 24576 + (p) * 8192; \
        async16(agp0 + (kk), Ad + c0b); \
        async16(agp1 + (kk), Ad + c1b); \
        async16(bgp0 + (kk), Bd + c0b); \
        async16(bgp1 + (kk), Bd + c1b); \
    } while (0)
    #define COMPUTE1(p) do { \
        const u16* Ab = SM + (p) * 4096; \
        const u16* Bb = SM + 12288 + (p) * 4096; \
        bf16x8 af[4], bfr[4]; \
        _Pragma("unroll") \
        for (int i = 0; i < 4; i++) af[i] = *(const bf16x8*)&Ab[(wm + i * 16 + fm) * 32 + slot]; \
        _Pragma("unroll") \
        for (int j2 = 0; j2 < 4; j2++) bfr[j2] = *(const bf16x8*)&Bb[(wn + j2 * 16 + fm) * 32 + slot]; \
        _Pragma("unroll") \
        for (int i = 0; i < 4; i++) \
            _Pragma("unroll") \
            for (int j2 = 0; j2 < 4; j2++) \
                acc[i][j2] = __builtin_amdgcn_mfma_f32_16x16x32_bf16(af[i], bfr[j2], acc[i][j2], 0, 0, 0); \
    } while (0)

    // K = 768 -> 24 tiles of 32 cols
    STAGE1(0, 0);
    STAGE1(1, 32);
    int q0 = 0, q1 = 1, q2 = 2;
    for (int t = 0; t < 22; ++t) {
        PWAIT4;                       // tile t landed (t+1 still flying), LDS reads drained
        STAGE1(q2, (t + 2) * 32);     // buf q2 free: computed >=1 barrier ago
        COMPUTE1(q0);
        int tmp = q0; q0 = q1; q1 = q2; q2 = tmp;
    }
    PWAIT4; COMPUTE1(q0);             // tile 22
    PWAIT0; COMPUTE1(q1);             // tile 23 (drain)
    #undef STAGE1
    #undef COMPUTE1
    __syncthreads();                  // all waves done with SM before epilogue reuse

    // ---- epilogue: gelu+cvt -> per-wave swizzled LDS tile -> coalesced uint4 stores ----
    int rbase = (lane >> 4) * 4;
    u16* tb = SM + w * 4096;          // 64x64 u16 (8 KB), XOR-swizzled by (m&7)
    #pragma unroll
    for (int i = 0; i < 4; i++)
        #pragma unroll
        for (int j2 = 0; j2 < 4; j2++)
            #pragma unroll
            for (int r = 0; r < 4; r++) {
                int m_l = i * 16 + rbase + r;
                int f_l = j2 * 16 + fm;
                u16 q = f2bf(gelu_f(acc[i][j2][r] + biasv[j2]));
                tb[m_l * 64 + ((((f_l >> 3) ^ (m_l & 7)) << 3) | (f_l & 7))] = q;
            }
    __syncthreads();
    #pragma unroll
    for (int s = 0; s < 8; s++) {
        int m_l = s * 8 + (lane >> 3);
        int c = lane & 7;
        uint4 vv = *(const uint4*)&tb[m_l * 64 + ((c ^ (m_l & 7)) << 3)];
        int m = m0 + wm + m_l;
        if (m < cnt)
            *(uint4*)&h[(size_t)(off + m) * F_ + n0 + wn + c * 8] = vv;
    }
}

// ---------------- GEMM2: out[token] += (h @ W2[e] + b2[e]) * weight (atomic combine) ----------------
// Same 3-buffer counted-vmcnt pipeline. K-split reverted (R2: atomic doubling regressed).
__global__ __launch_bounds__(256) void k_gemm2(
    const u16* __restrict__ h, const u16* __restrict__ w2t,
    const float* __restrict__ b2,
    const int* __restrict__ counts, const int* __restrict__ offsets,
    const int* __restrict__ tile_list,
    const int* __restrict__ assign_token, const float* __restrict__ assign_weight,
    float* __restrict__ out)
{
    int bid = blockIdx.x;
    int xcd = bid & 7;
    int j = bid >> 3;
    int nx = j % 6;
    int mloc = j / 6;
    int nt = tile_list[0];
    int ok;
    int mt = xcd_tile(xcd, mloc, nt, &ok);
    if (!ok) return;
    int packed = tile_list[1 + mt];
    int e = packed & 0xff;
    int m0 = packed >> 8;
    int cnt = counts[e];
    int off = offsets[e];
    int n0 = nx * 128;

    __shared__ __align__(16) u16 SM[24576];
    char* smb = (char*)SM;

    int tid = threadIdx.x;
    int w = tid >> 6, lane = tid & 63;
    int rA = lane >> 2;
    int colk = ((lane & 3) ^ (rA & 3)) * 8;
    int r0 = (w * 2 + 0) * 16 + rA;
    int r1 = (w * 2 + 1) * 16 + rA;

    int c0b = __builtin_amdgcn_readfirstlane((w * 2 + 0) * 1024);
    int c1b = __builtin_amdgcn_readfirstlane((w * 2 + 1) * 1024);

    // rows beyond cnt over-read hbuf slack rows (allocated), masked at store
    const u16* agp0 = h + (size_t)(off + m0 + r0) * F_ + colk;
    const u16* agp1 = h + (size_t)(off + m0 + r1) * F_ + colk;
    const u16* bgp0 = w2t + ((size_t)e * D_ + n0 + r0) * F_ + colk;
    const u16* bgp1 = w2t + ((size_t)e * D_ + n0 + r1) * F_ + colk;

    f32x4 acc[4][4];
    #pragma unroll
    for (int i = 0; i < 4; i++)
        #pragma unroll
        for (int j2 = 0; j2 < 4; j2++) acc[i][j2] = (f32x4){0.f, 0.f, 0.f, 0.f};

    int wm = (w >> 1) * 64, wn = (w & 1) * 64;
    int fm = lane & 15;
    int slot = ((lane >> 4) ^ (fm & 3)) * 8;
    int rbase = (lane >> 4) * 4;

    // Prefetch ALL epilogue VMEM (bias + token/weight gathers) BEFORE any STAGE
    // and pin retired — keeps the loop's vmcnt counts exact (no stray VMEM).
    float biasv[4];
    #pragma unroll
    for (int j2 = 0; j2 < 4; j2++) {
        biasv[j2] = b2[e * D_ + n0 + wn + j2 * 16 + fm];
        asm volatile("" : "+v"(biasv[j2]));
    }
    int tokv[4][4]; float wgtv[4][4];
    #pragma unroll
    for (int i = 0; i < 4; i++)
        #pragma unroll
        for (int r = 0; r < 4; r++) {
            int m = m0 + wm + i * 16 + rbase + r;
            int mr = (m < cnt) ? m : (cnt - 1);          // clamp: stay in-bounds
            tokv[i][r] = assign_token[off + mr];
            wgtv[i][r] = assign_weight[off + mr];
            asm volatile("" : "+v"(tokv[i][r]));
            asm volatile("" : "+v"(wgtv[i][r]));
        }

    #define STAGE2(p, kk) do { \
        char* Ad = smb + (p) * 8192; \
        char* Bd = smb + 24576 + (p) * 8192; \
        async16(agp0 + (kk), Ad + c0b); \
        async16(agp1 + (kk), Ad + c1b); \
        async16(bgp0 + (kk), Bd + c0b); \
        async16(bgp1 + (kk), Bd + c1b); \
    } while (0)
    #define COMPUTE2(p) do { \
        const u16* Ab = SM + (p) * 4096; \
        const u16* Bb = SM + 12288 + (p) * 4096; \
        bf16x8 af[4], bfr[4]; \
        _Pragma("unroll") \
        for (int i = 0; i < 4; i++) af[i] = *(const bf16x8*)&Ab[(wm + i * 16 + fm) * 32 + slot]; \
        _Pragma("unroll") \
        for (int j2 = 0; j2 < 4; j2++) bfr[j2] = *(const bf16x8*)&Bb[(wn + j2 * 16 + fm) * 32 + slot]; \
        _Pragma("unroll") \
        for (int i = 0; i < 4; i++) \
            _Pragma("unroll") \
            for (int j2 = 0; j2 < 4; j2++) \
                acc[i][j2] = __builtin_amdgcn_mfma_f32_16x16x32_bf16(af[i], bfr[j2], acc[i][j2], 0, 0, 0); \
    } while (0)

    // K = 3072 -> 96 tiles of 32 cols
    STAGE2(0, 0);
    STAGE2(1, 32);
    int q0 = 0, q1 = 1, q2 = 2;
    for (int t = 0; t < 94; ++t) {
        PWAIT4;
        STAGE2(q2, (t + 2) * 32);
        COMPUTE2(q0);
        int tmp = q0; q0 = q1; q1 = q2; q2 = tmp;
    }
    PWAIT4; COMPUTE2(q0);             // tile 94
    PWAIT0; COMPUTE2(q1);             // tile 95 (drain)
    #undef STAGE2
    #undef COMPUTE2

    #pragma unroll
    for (int i = 0; i < 4; i++)
        #pragma unroll
        for (int r = 0; r < 4; r++) {
            int m = m0 + wm + i * 16 + rbase + r;
            if (m < cnt) {
                float* orow = out + (size_t)tokv[i][r] * D_ + n0 + wn + fm;
                float wg = wgtv[i][r];
                #pragma unroll
                for (int j2 = 0; j2 < 4; j2++)
                    unsafeAtomicAdd(orow + j2 * 16, (acc[i][j2][r] + biasv[j2]) * wg);
            }
        }
}

extern "C" void kernel_launch(void* const* d_in, const int* in_sizes, int n_in,
                              void* d_out, int out_size, void* d_ws, size_t ws_size,
                              hipStream_t stream)
{
    const float* x  = (const float*)d_in[0];
    const float* Wr = (const float*)d_in[1];
    const float* W1 = (const float*)d_in[2];
    const float* b1 = (const float*)d_in[3];
    const float* W2 = (const float*)d_in[4];
    const float* b2 = (const float*)d_in[5];
    float* out = (float*)d_out;

    char* base = (char*)d_ws;
    size_t o = 0;
    auto alloc = [&](size_t bytes) {
        char* r = base + o;
        o += (bytes + 255) & ~(size_t)255;
        return r;
    };
    int*   counts        = (int*)  alloc(E_ * 4);
    int*   cursors       = (int*)  alloc(E_ * 4);
    int*   offsets       = (int*)  alloc(E_ * 4);
    int*   tile_list     = (int*)  alloc(256 * 4);
    float* usage_part    = (float*)alloc((size_t)RBLK * E_ * 4);
    float* z_part        = (float*)alloc((size_t)RBLK * 4);
    int*   hist_part     = (int*)  alloc((size_t)RBLK * E_ * 4);
    int*   tk_idx        = (int*)  alloc((size_t)NTOK * 2 * 4);
    float* tk_w          = (float*)alloc((size_t)NTOK * 2 * 4);
    int*   assign_token  = (int*)  alloc((size_t)NASSIGN * 4);
    float* assign_weight = (float*)alloc((size_t)NASSIGN * 4);
    u16*   xb            = (u16*)  alloc((size_t)NTOK * D_ * 2);
    u16*   w1t           = (u16*)  alloc((size_t)E_ * F_ * D_ * 2);
    u16*   w2t           = (u16*)  alloc((size_t)E_ * D_ * F_ * 2);
    u16*   hbuf          = (u16*)  alloc((size_t)(NASSIGN + 128) * F_ * 2);  // +128 over-read slack

    hipMemsetAsync(d_out, 0, (size_t)out_size * 4, stream);
    k_cvt_x<<<dim3(NTOK * D_ / 1024), dim3(256), 0, stream>>>(x, xb);
    k_tcvt<<<dim3(F_ / 64, D_ / 64, E_), dim3(256), 0, stream>>>(W1, w1t, D_, F_);
    k_tcvt<<<dim3(D_ / 64, F_ / 64, E_), dim3(256), 0, stream>>>(W2, w2t, F_, D_);
    k_router<<<dim3(RBLK), dim3(256), 0, stream>>>(x, Wr, usage_part, z_part, hist_part, tk_idx, tk_w);
    k_finalize<<<dim3(1), dim3(256), 0, stream>>>(usage_part, z_part, hist_part, counts, offsets,
                                                  cursors, tile_list, out + (size_t)NTOK * D_);
    k_fill<<<dim3(FBLK), dim3(256), 0, stream>>>(tk_idx, tk_w, offsets, cursors, assign_token, assign_weight);
    k_gemm1<<<dim3(8 * 17 * (F_ / 128)), dim3(256), 0, stream>>>(xb, w1t, b1, counts, offsets, tile_list,
                                                                 assign_token, hbuf);
    k_gemm2<<<dim3(8 * 17 * (D_ / 128)), dim3(256), 0, stream>>>(hbuf, w2t, b2, counts, offsets, tile_list,
                                                                 assign_token, assign_weight, out);
}